// Round 18
// baseline (493.853 us; speedup 1.0000x reference)
//
#include <hip/hip_runtime.h>
#include <hip/hip_bf16.h>

#define NN 100000
#define EE 800000
#define THRV 0.1f
#define DELTA 0.004f
#define EPSV 1e-8f
#define GEMMB 3125                   // gemm_nh blocks in fused sim1gemm launch
#define GB2 3125                     // gemm_nc blocks in fused simgemm2 launch

#define ATOMIC_ADD_F32 unsafeAtomicAdd

__device__ inline int dot4(int a, int b, int c) {
#if __has_builtin(__builtin_amdgcn_sdot4)
    return __builtin_amdgcn_sdot4(a, b, c, false);
#else
    int s = c;
    #pragma unroll
    for (int k = 0; k < 4; k++) {
        int av = (a << (24 - 8 * k)) >> 24;
        int bv = (b << (24 - 8 * k)) >> 24;
        s += av * bv;
    }
    return s;
#endif
}

__device__ inline unsigned short f2bf(float f) {
    unsigned int u = __float_as_uint(f);
    u += 0x7fffu + ((u >> 16) & 1u);
    return (unsigned short)(u >> 16);
}

__device__ inline float bf2f(unsigned short s) {
    return __uint_as_float(((unsigned int)s) << 16);
}

// ======= normalize: x -> int8 rows (xq) + scale rs + norms + degL1=1 + cnt=0 =======

__global__ __launch_bounds__(256) void normalize_k(const float* __restrict__ x,
                                                   unsigned short* __restrict__ xq,
                                                   float* __restrict__ rs,
                                                   float* __restrict__ norms_x,
                                                   float* __restrict__ degL1,
                                                   int* __restrict__ cnt) {
    int node = blockIdx.x * 4 + (threadIdx.x >> 6);
    int lane = threadIdx.x & 63;
    float2 v = reinterpret_cast<const float2*>(x)[(size_t)node * 64 + lane];
    float ss = v.x * v.x + v.y * v.y;
    float am = fmaxf(fabsf(v.x), fabsf(v.y));
    #pragma unroll
    for (int off = 32; off; off >>= 1) {
        ss += __shfl_xor(ss, off);
        am = fmaxf(am, __shfl_xor(am, off));
    }
    float norm = fmaxf(sqrtf(ss), EPSV);
    am = fmaxf(am, 1e-12f);
    float qs = 127.0f / am;
    int q0 = __float2int_rn(v.x * qs);
    int q1 = __float2int_rn(v.y * qs);
    xq[(size_t)node * 64 + lane] = (unsigned short)((q0 & 0xff) | ((q1 & 0xff) << 8));
    if (lane == 0) {
        norms_x[node] = norm;
        rs[node] = am / (127.0f * norm);
        degL1[node] = 1.0f;
        degL1[node + NN] = 1.0f;
        cnt[node] = 0;
        cnt[node + NN] = 0;
    }
}

// ===== quantize W1 (128x128) and W2 (128x40) per column in one launch =====
// blocks 0..127 -> W1 col; blocks 128..167 -> W2 col-128

__global__ __launch_bounds__(64) void quantW12_k(const float* __restrict__ W1,
                                                 int* __restrict__ Wq1,
                                                 float* __restrict__ wcs1,
                                                 const float* __restrict__ W2,
                                                 int* __restrict__ Wq2,
                                                 float* __restrict__ wcs2) {
    const float* W; int* Wq; float* wcs; int C, col;
    if (blockIdx.x < 128) { W = W1; Wq = Wq1; wcs = wcs1; C = 128; col = blockIdx.x; }
    else { W = W2; Wq = Wq2; wcs = wcs2; C = 40; col = blockIdx.x - 128; }
    int t = threadIdx.x;
    float am = fmaxf(fabsf(W[t * C + col]), fabsf(W[(t + 64) * C + col]));
    #pragma unroll
    for (int off = 32; off; off >>= 1) am = fmaxf(am, __shfl_xor(am, off));
    am = fmaxf(am, 1e-20f);
    float qs = 127.0f / am;
    if (t < 32) {
        int p = 0;
        #pragma unroll
        for (int tt = 0; tt < 4; tt++) {
            int q = __float2int_rn(W[(4 * t + tt) * C + col] * qs);
            p |= (q & 0xff) << (8 * tt);
        }
        Wq[t * C + col] = p;
    }
    if (t == 0) wcs[col] = am / 127.0f;
}

// ===== FUSED: int8 gemm_nh (blocks 0..GEMMB) + pass-1 edge sim (rest) =====
// LDS exactly 20 KB -> 8 blocks/CU, occupancy-neutral for the edge path.

__global__ __launch_bounds__(256) void sim1gemm_k(
        const unsigned short* __restrict__ xq, const float* __restrict__ rs,
        const float* __restrict__ x, const float* __restrict__ norms_x,
        const int* __restrict__ r1, const int* __restrict__ c1,
        const int* __restrict__ r2, const int* __restrict__ c2,
        float* __restrict__ ews, float* __restrict__ degL1,
        int* __restrict__ cnt,
        const int* __restrict__ Wq, const float* __restrict__ wcs,
        unsigned int* __restrict__ hq, float* __restrict__ hrs) {
    __shared__ int WsQ[32 * 128];     // 16 KB
    __shared__ int XsQ[32 * 32];      // 4 KB   (total 20 KB exactly)
    int tid = threadIdx.x;

    if (blockIdx.x < GEMMB) {
        // ---------------- int8 gemm path ----------------
        const int* xqi = (const int*)xq;
        int row0 = blockIdx.x * 32;
        {
            int4* W4 = reinterpret_cast<int4*>(WsQ);
            const int4* Wg4 = reinterpret_cast<const int4*>(Wq);
            #pragma unroll
            for (int i = 0; i < 4; i++) W4[tid + 256 * i] = Wg4[tid + 256 * i];
            int r = tid >> 3, p = tid & 7;
            reinterpret_cast<int4*>(XsQ)[tid] =
                reinterpret_cast<const int4*>(xqi + (size_t)(row0 + r) * 32)[p];
        }
        __syncthreads();
        int cg = tid & 31;     // cols 4cg..4cg+3
        int rl = tid >> 5;     // rows rl, rl+8, rl+16, rl+24
        int4 acc[4];
        #pragma unroll
        for (int i = 0; i < 4; i++) acc[i] = make_int4(0, 0, 0, 0);
        for (int k4 = 0; k4 < 32; k4++) {
            int4 wv = reinterpret_cast<const int4*>(WsQ + k4 * 128)[cg];
            #pragma unroll
            for (int r4 = 0; r4 < 4; r4++) {
                int xv = XsQ[(rl + 8 * r4) * 32 + k4];
                acc[r4].x = dot4(xv, wv.x, acc[r4].x);
                acc[r4].y = dot4(xv, wv.y, acc[r4].y);
                acc[r4].z = dot4(xv, wv.z, acc[r4].z);
                acc[r4].w = dot4(xv, wv.w, acc[r4].w);
            }
        }
        float4 wc = reinterpret_cast<const float4*>(wcs)[cg];   // L2-hot global
        #pragma unroll
        for (int r4 = 0; r4 < 4; r4++) {
            int grow = row0 + rl + 8 * r4;
            float xscale = rs[grow] * norms_x[grow];   // = am_row/127
            float fx = (float)acc[r4].x * xscale * wc.x;
            float fy = (float)acc[r4].y * xscale * wc.y;
            float fz = (float)acc[r4].z * xscale * wc.z;
            float fw = (float)acc[r4].w * xscale * wc.w;
            float am = fmaxf(fmaxf(fabsf(fx), fabsf(fy)), fmaxf(fabsf(fz), fabsf(fw)));
            #pragma unroll
            for (int off = 1; off < 32; off <<= 1) am = fmaxf(am, __shfl_xor(am, off));
            am = fmaxf(am, 1e-20f);
            float qs = 127.0f / am;
            int q0 = __float2int_rn(fx * qs);
            int q1 = __float2int_rn(fy * qs);
            int q2 = __float2int_rn(fz * qs);
            int q3 = __float2int_rn(fw * qs);
            unsigned int u = (q0 & 0xff) | ((q1 & 0xff) << 8) |
                             ((q2 & 0xff) << 16) | ((q3 & 0xff) << 24);
            hq[(size_t)grow * 32 + cg] = u;
            if (cg == 0) hrs[grow] = am / 127.0f;
        }
        return;
    }

    // ---------------- edge path (8 lanes/edge) ----------------
    int e = (blockIdx.x - GEMMB) * 32 + (tid >> 3);
    int q = tid & 7;
    int rnode, cnode, gr;
    if (e < EE) { rnode = r1[e]; cnode = c1[e]; gr = rnode; }
    else { int ee = e - EE; rnode = r2[ee]; cnode = c2[ee]; gr = NN + rnode; }
    int role = q >> 2;
    int j = q & 3;
    int node = role ? cnode : rnode;
    const uint4* base = reinterpret_cast<const uint4*>(xq) + (size_t)node * 8 + j * 2;
    uint4 v0 = base[0];
    uint4 v1 = base[1];
    uint4 p0, p1;
    p0.x = (unsigned)__shfl_xor((int)v0.x, 4);
    p0.y = (unsigned)__shfl_xor((int)v0.y, 4);
    p0.z = (unsigned)__shfl_xor((int)v0.z, 4);
    p0.w = (unsigned)__shfl_xor((int)v0.w, 4);
    p1.x = (unsigned)__shfl_xor((int)v1.x, 4);
    p1.y = (unsigned)__shfl_xor((int)v1.y, 4);
    p1.z = (unsigned)__shfl_xor((int)v1.z, 4);
    p1.w = (unsigned)__shfl_xor((int)v1.w, 4);
    int d = dot4((int)v0.x, (int)p0.x, 0);
    d = dot4((int)v0.y, (int)p0.y, d);
    d = dot4((int)v0.z, (int)p0.z, d);
    d = dot4((int)v0.w, (int)p0.w, d);
    d = dot4((int)v1.x, (int)p1.x, d);
    d = dot4((int)v1.y, (int)p1.y, d);
    d = dot4((int)v1.z, (int)p1.z, d);
    d = dot4((int)v1.w, (int)p1.w, d);
    d += __shfl_xor(d, 1);
    d += __shfl_xor(d, 2);
    float sim = (float)d * rs[rnode] * rs[cnode];
    if (fabsf(sim - THRV) <= DELTA) {
        const float4* xa = reinterpret_cast<const float4*>(x + (size_t)rnode * 128);
        const float4* xb = reinterpret_cast<const float4*>(x + (size_t)cnode * 128);
        float df = 0.f;
        #pragma unroll
        for (int t = 0; t < 4; t++) {
            float4 a = xa[q + 8 * t];
            float4 bb = xb[q + 8 * t];
            df += a.x * bb.x + a.y * bb.y + a.z * bb.z + a.w * bb.w;
        }
        df += __shfl_xor(df, 1);
        df += __shfl_xor(df, 2);
        df += __shfl_xor(df, 4);
        sim = df / (norms_x[rnode] * norms_x[cnode]);
    }
    float w = (sim >= THRV) ? sim : 0.0f;
    if (q == 0) {
        ews[e] = w;
        if (w != 0.0f) {
            ATOMIC_ADD_F32(&degL1[gr], w);
            atomicAdd(&cnt[gr], 1);
        }
    }
}

// ================= scan (cnt -> start exclusive prefix) =================

__global__ __launch_bounds__(512) void scan1_k(const int* __restrict__ in,
                                               int* __restrict__ out,
                                               int* __restrict__ partials, int n) {
    __shared__ int a[1024], b[1024];
    int t = threadIdx.x;
    int base = blockIdx.x * 1024;
    a[t]       = (base + t       < n) ? in[base + t]       : 0;
    a[t + 512] = (base + t + 512 < n) ? in[base + t + 512] : 0;
    __syncthreads();
    int* src = a; int* dst = b;
    for (int off = 1; off < 1024; off <<= 1) {
        #pragma unroll
        for (int q = 0; q < 2; q++) {
            int i = t + q * 512;
            int v = src[i];
            if (i >= off) v += src[i - off];
            dst[i] = v;
        }
        __syncthreads();
        int* tmp = src; src = dst; dst = tmp;
    }
    for (int q = 0; q < 2; q++) {
        int i = t + q * 512;
        if (base + i < n) out[base + i] = i ? src[i - 1] : 0;
    }
    if (t == 0) partials[blockIdx.x] = src[1023];
}

__global__ __launch_bounds__(256) void scan2_k(int* __restrict__ partials, int m) {
    __shared__ int a[256], b[256];
    int t = threadIdx.x;
    a[t] = (t < m) ? partials[t] : 0;
    __syncthreads();
    int* src = a; int* dst = b;
    for (int off = 1; off < 256; off <<= 1) {
        int v = src[t];
        if (t >= off) v += src[t - off];
        dst[t] = v;
        __syncthreads();
        int* tmp = src; src = dst; dst = tmp;
    }
    if (t < m) partials[t] = t ? src[t - 1] : 0;
}

// scan3 + dinvh precompute: dinvh[i] = rsqrt(degL1[i]) * hrs[i % NN]

__global__ void scan3_k(int* __restrict__ start, int* __restrict__ next,
                        const int* __restrict__ partials,
                        const int* __restrict__ cnt,
                        const float* __restrict__ degL1,
                        const float* __restrict__ hrs,
                        float* __restrict__ dinvh, int n) {
    int i = blockIdx.x * 256 + threadIdx.x;
    if (i < n) {
        int v = start[i] + partials[i >> 10];
        start[i] = v;
        next[i] = v;
        if (i == n - 1) start[n] = v + cnt[i];
        int node = (i < NN) ? i : i - NN;
        dinvh[i] = rsqrtf(degL1[i]) * hrs[node];
    }
}

// ===== scatter alive edges: acw = {col, w * dinvh[sb+col]} =====

__global__ void scatter_alive_k(const int* __restrict__ r1, const int* __restrict__ c1,
                                const int* __restrict__ r2, const int* __restrict__ c2,
                                const float* __restrict__ ews,
                                const float* __restrict__ dinvh,
                                int* __restrict__ next, int2* __restrict__ acw) {
    int e = blockIdx.x * 256 + threadIdx.x;
    float w = ews[e];
    if (w == 0.0f) return;
    int gr, c, sb;
    if (e < EE) { gr = r1[e]; c = c1[e]; sb = 0; }
    else        { gr = NN + r2[e - EE]; c = c2[e - EE]; sb = NN; }
    int pos = atomicAdd(&next[gr], 1);
    int2 rec;
    rec.x = c;
    rec.y = __float_as_int(w * dinvh[sb + c]);
    acw[pos] = rec;
}

// ===== CSR aggregate D=128 over int8 h; writes bf16 agg + int8 agg + scales =====

__global__ __launch_bounds__(256) void agg128_fused_k(
        const unsigned short* __restrict__ hq16, const float* __restrict__ hrs,
        const int* __restrict__ start, const int2* __restrict__ acw,
        const float* __restrict__ degL1, const float* __restrict__ bias,
        unsigned int* __restrict__ aggb, unsigned short* __restrict__ xq2,
        float* __restrict__ rs2, float* __restrict__ norms_l2,
        float* __restrict__ degL2) {
    int gr = blockIdx.x * 4 + (threadIdx.x >> 6);
    int lane = threadIdx.x & 63;
    int rnode = (gr < NN) ? gr : gr - NN;
    int j0 = start[gr], j1 = start[gr + 1];
    float2 acc = make_float2(0.f, 0.f);
    for (int j = j0; j < j1; j++) {
        int2 rec = acw[j];
        float wv = __int_as_float(rec.y);        // includes hrs[col]
        unsigned short hv = hq16[(size_t)rec.x * 64 + lane];
        acc.x += (float)(char)(hv & 0xff) * wv;
        acc.y += (float)(char)(hv >> 8) * wv;
    }
    float dr = rsqrtf(degL1[gr]);
    float hr = hrs[rnode];
    unsigned short hs = hq16[(size_t)rnode * 64 + lane];
    float hx = (float)(char)(hs & 0xff) * hr;
    float hy = (float)(char)(hs >> 8) * hr;
    float2 bb = reinterpret_cast<const float2*>(bias)[lane];
    float vx = fmaxf(acc.x * dr + hx * dr * dr + bb.x, 0.0f);
    float vy = fmaxf(acc.y * dr + hy * dr * dr + bb.y, 0.0f);
    aggb[(size_t)gr * 64 + lane] =
        (unsigned int)f2bf(vx) | ((unsigned int)f2bf(vy) << 16);
    float ss = vx * vx + vy * vy;
    float am = fmaxf(vx, vy);                     // non-negative rows
    #pragma unroll
    for (int off = 32; off; off >>= 1) {
        ss += __shfl_xor(ss, off);
        am = fmaxf(am, __shfl_xor(am, off));
    }
    float norm = fmaxf(sqrtf(ss), EPSV);
    am = fmaxf(am, 1e-12f);
    float qs = 127.0f / am;
    int q0 = __float2int_rn(vx * qs);
    int q1 = __float2int_rn(vy * qs);
    xq2[(size_t)gr * 64 + lane] = (unsigned short)((q0 & 0xff) | ((q1 & 0xff) << 8));
    if (lane == 0) {
        rs2[gr] = am / (127.0f * norm);
        norms_l2[gr] = norm;
        degL2[gr] = 1.0f;
    }
}

// ===== FUSED: gemm_nc (blocks 0..GB2) + pass-2 edge sim (rest) =====

__global__ __launch_bounds__(256) void simgemm2_k(
        const unsigned short* __restrict__ xq2, const float* __restrict__ rs2,
        const unsigned int* __restrict__ aggb, const float* __restrict__ norms_l2,
        const int* __restrict__ start, int2* __restrict__ acw,
        float* __restrict__ degL2,
        const int* __restrict__ Wq2, const float* __restrict__ wcs2,
        unsigned short* __restrict__ h2b, int n) {
    __shared__ int XsQ[64 * 33];      // 8.25 KB
    __shared__ int WsQ2[32 * 40];     // 5 KB
    __shared__ float wcss[40];
    __shared__ float rsc[64];
    int tid = threadIdx.x;

    if (blockIdx.x < GB2) {
        // ---------------- gemm_nc path ----------------
        const int* xq2i = (const int*)xq2;
        int row0 = blockIdx.x * 64;
        for (int i = tid; i < 32 * 40; i += 256) WsQ2[i] = Wq2[i];
        if (tid < 40) wcss[tid] = wcs2[tid];
        if (tid < 64) {
            int g = row0 + tid;
            rsc[tid] = rs2[g] * norms_l2[g];    // = am_row/127
        }
        #pragma unroll
        for (int i = 0; i < 2; i++) {
            int idx = tid + 256 * i;            // 0..511 int4s
            int rr = idx >> 3, p = idx & 7;
            int4 v = reinterpret_cast<const int4*>(xq2i + (size_t)(row0 + rr) * 32)[p];
            int* dst = &XsQ[rr * 33 + p * 4];
            dst[0] = v.x; dst[1] = v.y; dst[2] = v.z; dst[3] = v.w;
        }
        __syncthreads();
        int c5 = tid & 7;
        int r  = tid >> 3;
        int acc0[5] = {0, 0, 0, 0, 0}, acc1[5] = {0, 0, 0, 0, 0};
        for (int k4 = 0; k4 < 32; k4++) {
            int xv0 = XsQ[r * 33 + k4];
            int xv1 = XsQ[(r + 32) * 33 + k4];
            #pragma unroll
            for (int c = 0; c < 5; c++) {
                int wv = WsQ2[k4 * 40 + c5 * 5 + c];
                acc0[c] = dot4(xv0, wv, acc0[c]);
                acc1[c] = dot4(xv1, wv, acc1[c]);
            }
        }
        float s0 = rsc[r], s1 = rsc[r + 32];
        int g0 = row0 + r, g1 = row0 + r + 32;
        for (int c = 0; c < 5; c++) {
            float wc = wcss[c5 * 5 + c];
            h2b[(size_t)g0 * 64 + c5 * 5 + c] = f2bf((float)acc0[c] * s0 * wc);
            h2b[(size_t)g1 * 64 + c5 * 5 + c] = f2bf((float)acc1[c] * s1 * wc);
        }
        return;
    }

    // ---------------- sim2 path ----------------
    int gr = (blockIdx.x - GB2) * 4 + (tid >> 6);
    int lane = tid & 63;
    int j0 = start[gr], j1 = start[gr + 1];
    if (j0 == j1) return;
    int set_base = (gr < NN) ? 0 : NN;
    unsigned int au = xq2[(size_t)gr * 64 + lane];
    int a0 = ((int)(au << 24)) >> 24;
    int a1 = ((int)((au << 16) & 0xff000000u)) >> 24;
    float ra = rs2[gr];
    float nr = norms_l2[gr];
    float sum = 0.f;
    for (int j = j0; j < j1; j++) {
        int2 rec = acw[j];
        int cg = set_base + rec.x;
        unsigned int bu = xq2[(size_t)cg * 64 + lane];
        int b0 = ((int)(bu << 24)) >> 24;
        int b1 = ((int)((bu << 16) & 0xff000000u)) >> 24;
        int d = a0 * b0 + a1 * b1;
        #pragma unroll
        for (int off = 32; off; off >>= 1) d += __shfl_xor(d, off);
        float sim = (float)d * ra * rs2[cg];
        if (fabsf(sim - THRV) <= DELTA) {
            unsigned int av = aggb[(size_t)gr * 64 + lane];
            unsigned int bv = aggb[(size_t)cg * 64 + lane];
            float df = bf2f((unsigned short)(av & 0xffff)) *
                       bf2f((unsigned short)(bv & 0xffff)) +
                       bf2f((unsigned short)(av >> 16)) *
                       bf2f((unsigned short)(bv >> 16));
            #pragma unroll
            for (int off = 32; off; off >>= 1) df += __shfl_xor(df, off);
            sim = df / (nr * norms_l2[cg]);
        }
        float w2 = (sim >= THRV) ? sim : 0.0f;
        if (lane == 0) acw[j].y = __float_as_int(w2);
        sum += w2;
    }
    if (lane == 0) degL2[gr] = 1.0f + sum;
}

// ===== CSR aggregate D=40 over bf16 padded h2, fused finish -> f32 aggy =====

__global__ __launch_bounds__(256) void agg40_fused_k(
        const unsigned short* __restrict__ h2b, const int* __restrict__ start,
        const int2* __restrict__ acw, const float* __restrict__ degL2,
        const float* __restrict__ bias, float* __restrict__ aggy) {
    int gr = blockIdx.x * 4 + (threadIdx.x >> 6);
    int lane = threadIdx.x & 63;
    int set_base = (gr < NN) ? 0 : NN;
    int j0 = start[gr], j1 = start[gr + 1];
    bool act = lane < 40;
    float acc = 0.f;
    for (int j = j0; j < j1; j++) {
        int2 rec = acw[j];
        float w2 = __int_as_float(rec.y);
        if (w2 == 0.0f) continue;
        int cg = set_base + rec.x;
        float nv = w2 * rsqrtf(degL2[cg]);
        float hv = act ? bf2f(h2b[(size_t)cg * 64 + lane]) : 0.f;
        acc += hv * nv;
    }
    if (act) {
        float dr = rsqrtf(degL2[gr]);
        float self = bf2f(h2b[(size_t)gr * 64 + lane]);
        aggy[(size_t)gr * 40 + lane] = acc * dr + self * dr * dr + bias[lane];
    }
}

// ================= fusion + log_softmax (thread per node) =================

__global__ __launch_bounds__(256) void fusion_k(const float* __restrict__ y1,
                                                const float* __restrict__ y2,
                                                const float* __restrict__ W1,
                                                const float* __restrict__ b1,
                                                const float* __restrict__ W2,
                                                float* __restrict__ out, int n) {
    __shared__ float W1s[40 * 40];
    __shared__ float b1s[40];
    __shared__ float W2s[40];
    int tid = threadIdx.x;
    for (int i = tid; i < 1600; i += 256) W1s[i] = W1[i];
    if (tid < 40) { b1s[tid] = b1[tid]; W2s[tid] = W2[tid]; }
    __syncthreads();
    int i = blockIdx.x * 256 + tid;
    if (i >= n) return;
    float z1[40], z2[40];
    const float4* y14 = reinterpret_cast<const float4*>(y1 + (size_t)i * 40);
    const float4* y24 = reinterpret_cast<const float4*>(y2 + (size_t)i * 40);
    #pragma unroll
    for (int q = 0; q < 10; q++) {
        float4 a = y14[q], b = y24[q];
        z1[4 * q] = a.x; z1[4 * q + 1] = a.y; z1[4 * q + 2] = a.z; z1[4 * q + 3] = a.w;
        z2[4 * q] = b.x; z2[4 * q + 1] = b.y; z2[4 * q + 2] = b.z; z2[4 * q + 3] = b.w;
    }
    float w1 = 0.f, w2 = 0.f;
    for (int c = 0; c < 40; c++) {
        float s1 = b1s[c], s2 = b1s[c];
        for (int j = 0; j < 40; j++) {
            float ww = W1s[j * 40 + c];
            s1 += z1[j] * ww; s2 += z2[j] * ww;
        }
        float wa = W2s[c];
        w1 += tanhf(s1) * wa; w2 += tanhf(s2) * wa;
    }
    float m = fmaxf(w1, w2);
    float e1 = expf(w1 - m), e2 = expf(w2 - m);
    float inv = 1.0f / (e1 + e2);
    float be1 = e1 * inv, be2 = e2 * inv;
    float fu[40];
    float mx = -1e30f;
    #pragma unroll
    for (int c = 0; c < 40; c++) {
        fu[c] = be1 * z1[c] + be2 * z2[c];
        mx = fmaxf(mx, fu[c]);
    }
    float se = 0.f;
    #pragma unroll
    for (int c = 0; c < 40; c++) se += expf(fu[c] - mx);
    float ls = logf(se);
    float4* o4 = reinterpret_cast<float4*>(out + (size_t)i * 40);
    #pragma unroll
    for (int q = 0; q < 10; q++) {
        float4 v;
        v.x = fu[4 * q] - mx - ls; v.y = fu[4 * q + 1] - mx - ls;
        v.z = fu[4 * q + 2] - mx - ls; v.w = fu[4 * q + 3] - mx - ls;
        o4[q] = v;
    }
}

// ================= host =================

extern "C" void kernel_launch(void* const* d_in, const int* in_sizes, int n_in,
                              void* d_out, int out_size, void* d_ws, size_t ws_size,
                              hipStream_t stream) {
    (void)in_sizes; (void)n_in; (void)out_size; (void)ws_size;
    const float* x   = (const float*)d_in[0];
    const float* Wg1 = (const float*)d_in[1];
    const float* bg1 = (const float*)d_in[2];
    const float* Wg2 = (const float*)d_in[3];
    const float* bg2 = (const float*)d_in[4];
    const float* Wa1 = (const float*)d_in[5];
    const float* ba1 = (const float*)d_in[6];
    const float* Wa2 = (const float*)d_in[7];
    const int* ei1 = (const int*)d_in[8];
    const int* ei2 = (const int*)d_in[9];
    const int *r1 = ei1, *c1 = ei1 + EE;
    const int *r2 = ei2, *c2 = ei2 + EE;
    float* out = (float*)d_out;

    // ---- workspace carve (f32 words); ~155 MB ----
    float* wp = (float*)d_ws;
    float* norms_x  = wp;  wp += NN;
    float* norms_l2 = wp;  wp += 2 * NN;
    float* rs       = wp;  wp += NN;
    float* degL1    = wp;  wp += 2 * NN;
    float* degL2    = wp;  wp += 2 * NN;
    float* hrs      = wp;  wp += NN;
    float* dinvh    = wp;  wp += 2 * NN;
    int*   cnt      = (int*)wp;  wp += 2 * NN;
    int*   start    = (int*)wp;  wp += 2 * NN + 8;
    int*   next     = (int*)wp;  wp += 2 * NN;
    int*   partials = (int*)wp;  wp += 512;
    int*   Wq       = (int*)wp;  wp += 32 * 128;                 // packed int8 W_gc1
    float* wcs      = wp;  wp += 128;
    int*   Wq2      = (int*)wp;  wp += 32 * 40;                  // packed int8 W_gc2
    float* wcs2     = wp;  wp += 40;
    float* ews      = wp;  wp += 2 * EE;                         // rs2 overlays after scatter
    int2*  acw      = (int2*)wp; wp += (size_t)2 * 2 * EE;       // worst-case all alive
    unsigned int* hq = (unsigned int*)wp; wp += (size_t)NN * 32;    // NN x 128 int8
    unsigned short* h2b = (unsigned short*)wp; wp += (size_t)2 * NN * 32;  // 2N x 64 bf16
    unsigned int*   aggb = (unsigned int*)wp;  wp += (size_t)2 * NN * 64;  // 2N x 128 bf16
    unsigned short* xq2 = (unsigned short*)wp; wp += (size_t)2 * NN * 32;  // 2N x 128 int8
    unsigned short* xq = (unsigned short*)aggb;  // pass-1 int8 x rows (dead before aggb)
    float* rs2 = ews;                            // ews dead after scatter_alive
    float* aggy = (float*)aggb;                  // aggb dead after simgemm2

    const int twoN = 2 * NN;
    const int twoE = 2 * EE;
    const int scan_blocks = (twoN + 1023) / 1024;    // 196

    // ---- pass 1: quant weights + norms + (int8 gemm || edge sims) ----
    quantW12_k<<<168, 64, 0, stream>>>(Wg1, Wq, wcs, Wg2, Wq2, wcs2);
    normalize_k<<<NN / 4, 256, 0, stream>>>(x, xq, rs, norms_x, degL1, cnt);
    sim1gemm_k<<<GEMMB + twoE / 32, 256, 0, stream>>>(
        xq, rs, x, norms_x, r1, c1, r2, c2, ews, degL1, cnt, Wq, wcs, hq, hrs);

    // ---- CSR over alive edges (+ dinvh precompute) ----
    scan1_k<<<scan_blocks, 512, 0, stream>>>(cnt, start, partials, twoN);
    scan2_k<<<1, 256, 0, stream>>>(partials, scan_blocks);
    scan3_k<<<(twoN + 255) / 256, 256, 0, stream>>>(start, next, partials, cnt,
                                                    degL1, hrs, dinvh, twoN);
    scatter_alive_k<<<twoE / 256, 256, 0, stream>>>(r1, c1, r2, c2, ews, dinvh,
                                                    next, acw);

    // ---- layer 1 aggregate ----
    agg128_fused_k<<<twoN / 4, 256, 0, stream>>>((const unsigned short*)hq, hrs,
                                                 start, acw, degL1, bg1,
                                                 aggb, xq2, rs2, norms_l2, degL2);

    // ---- layer 2: fused (gemm_nc || edge_sim2) ----
    simgemm2_k<<<GB2 + twoN / 4, 256, 0, stream>>>(xq2, rs2, aggb, norms_l2,
                                                   start, acw, degL2,
                                                   Wq2, wcs2, h2b, twoN);
    agg40_fused_k<<<twoN / 4, 256, 0, stream>>>(h2b, start, acw, degL2, bg2, aggy);
    fusion_k<<<(NN + 255) / 256, 256, 0, stream>>>(aggy, aggy + (size_t)NN * 40,
                                                   Wa1, ba1, Wa2, out, NN);
}

// Round 19
// 403.907 us; speedup vs baseline: 1.2227x; 1.2227x over previous
//
#include <hip/hip_runtime.h>
#include <hip/hip_bf16.h>

#define NN 100000
#define EE 800000
#define THRV 0.1f
#define DELTA 0.004f
#define EPSV 1e-8f
#define GB2 3125                     // gemm_nc blocks in fused simgemm2 launch

#define ATOMIC_ADD_F32 unsafeAtomicAdd

__device__ inline int dot4(int a, int b, int c) {
#if __has_builtin(__builtin_amdgcn_sdot4)
    return __builtin_amdgcn_sdot4(a, b, c, false);
#else
    int s = c;
    #pragma unroll
    for (int k = 0; k < 4; k++) {
        int av = (a << (24 - 8 * k)) >> 24;
        int bv = (b << (24 - 8 * k)) >> 24;
        s += av * bv;
    }
    return s;
#endif
}

__device__ inline unsigned short f2bf(float f) {
    unsigned int u = __float_as_uint(f);
    u += 0x7fffu + ((u >> 16) & 1u);
    return (unsigned short)(u >> 16);
}

__device__ inline float bf2f(unsigned short s) {
    return __uint_as_float(((unsigned int)s) << 16);
}

// ======= normalize: x -> int8 rows (xq) + scale rs + norms + degL1=1 + cnt=0 =======

__global__ __launch_bounds__(256) void normalize_k(const float* __restrict__ x,
                                                   unsigned short* __restrict__ xq,
                                                   float* __restrict__ rs,
                                                   float* __restrict__ norms_x,
                                                   float* __restrict__ degL1,
                                                   int* __restrict__ cnt) {
    int node = blockIdx.x * 4 + (threadIdx.x >> 6);
    int lane = threadIdx.x & 63;
    float2 v = reinterpret_cast<const float2*>(x)[(size_t)node * 64 + lane];
    float ss = v.x * v.x + v.y * v.y;
    float am = fmaxf(fabsf(v.x), fabsf(v.y));
    #pragma unroll
    for (int off = 32; off; off >>= 1) {
        ss += __shfl_xor(ss, off);
        am = fmaxf(am, __shfl_xor(am, off));
    }
    float norm = fmaxf(sqrtf(ss), EPSV);
    am = fmaxf(am, 1e-12f);
    float qs = 127.0f / am;
    int q0 = __float2int_rn(v.x * qs);
    int q1 = __float2int_rn(v.y * qs);
    xq[(size_t)node * 64 + lane] = (unsigned short)((q0 & 0xff) | ((q1 & 0xff) << 8));
    if (lane == 0) {
        norms_x[node] = norm;
        rs[node] = am / (127.0f * norm);
        degL1[node] = 1.0f;
        degL1[node + NN] = 1.0f;
        cnt[node] = 0;
        cnt[node + NN] = 0;
    }
}

// ===== quantize W1 (128x128) and W2 (128x40) per column in one launch =====

__global__ __launch_bounds__(64) void quantW12_k(const float* __restrict__ W1,
                                                 int* __restrict__ Wq1,
                                                 float* __restrict__ wcs1,
                                                 const float* __restrict__ W2,
                                                 int* __restrict__ Wq2,
                                                 float* __restrict__ wcs2) {
    const float* W; int* Wq; float* wcs; int C, col;
    if (blockIdx.x < 128) { W = W1; Wq = Wq1; wcs = wcs1; C = 128; col = blockIdx.x; }
    else { W = W2; Wq = Wq2; wcs = wcs2; C = 40; col = blockIdx.x - 128; }
    int t = threadIdx.x;
    float am = fmaxf(fabsf(W[t * C + col]), fabsf(W[(t + 64) * C + col]));
    #pragma unroll
    for (int off = 32; off; off >>= 1) am = fmaxf(am, __shfl_xor(am, off));
    am = fmaxf(am, 1e-20f);
    float qs = 127.0f / am;
    if (t < 32) {
        int p = 0;
        #pragma unroll
        for (int tt = 0; tt < 4; tt++) {
            int q = __float2int_rn(W[(4 * t + tt) * C + col] * qs);
            p |= (q & 0xff) << (8 * tt);
        }
        Wq[t * C + col] = p;
    }
    if (t == 0) wcs[col] = am / 127.0f;
}

// ===== pass-1 edge sim (standalone): int8 rows, 8 lanes/edge =====

__global__ __launch_bounds__(256) void edge_sim1_k(
        const unsigned short* __restrict__ xq, const float* __restrict__ rs,
        const float* __restrict__ x, const float* __restrict__ norms_x,
        const int* __restrict__ r1, const int* __restrict__ c1,
        const int* __restrict__ r2, const int* __restrict__ c2,
        float* __restrict__ ews, float* __restrict__ degL1,
        int* __restrict__ cnt) {
    int tid = threadIdx.x;
    int e = blockIdx.x * 32 + (tid >> 3);            // 0..2E, 32 edges/block
    int q = tid & 7;
    int rnode, cnode, gr;
    if (e < EE) { rnode = r1[e]; cnode = c1[e]; gr = rnode; }
    else { int ee = e - EE; rnode = r2[ee]; cnode = c2[ee]; gr = NN + rnode; }
    int role = q >> 2;                                // 0: row node, 1: col node
    int j = q & 3;                                    // 16B chunk
    int node = role ? cnode : rnode;
    const uint4* base = reinterpret_cast<const uint4*>(xq) + (size_t)node * 8 + j * 2;
    uint4 v0 = base[0];
    uint4 v1 = base[1];
    uint4 p0, p1;
    p0.x = (unsigned)__shfl_xor((int)v0.x, 4);
    p0.y = (unsigned)__shfl_xor((int)v0.y, 4);
    p0.z = (unsigned)__shfl_xor((int)v0.z, 4);
    p0.w = (unsigned)__shfl_xor((int)v0.w, 4);
    p1.x = (unsigned)__shfl_xor((int)v1.x, 4);
    p1.y = (unsigned)__shfl_xor((int)v1.y, 4);
    p1.z = (unsigned)__shfl_xor((int)v1.z, 4);
    p1.w = (unsigned)__shfl_xor((int)v1.w, 4);
    int d = dot4((int)v0.x, (int)p0.x, 0);
    d = dot4((int)v0.y, (int)p0.y, d);
    d = dot4((int)v0.z, (int)p0.z, d);
    d = dot4((int)v0.w, (int)p0.w, d);
    d = dot4((int)v1.x, (int)p1.x, d);
    d = dot4((int)v1.y, (int)p1.y, d);
    d = dot4((int)v1.z, (int)p1.z, d);
    d = dot4((int)v1.w, (int)p1.w, d);
    d += __shfl_xor(d, 1);
    d += __shfl_xor(d, 2);
    float sim = (float)d * rs[rnode] * rs[cnode];
    if (fabsf(sim - THRV) <= DELTA) {
        const float4* xa = reinterpret_cast<const float4*>(x + (size_t)rnode * 128);
        const float4* xb = reinterpret_cast<const float4*>(x + (size_t)cnode * 128);
        float df = 0.f;
        #pragma unroll
        for (int t = 0; t < 4; t++) {
            float4 a = xa[q + 8 * t];
            float4 bb = xb[q + 8 * t];
            df += a.x * bb.x + a.y * bb.y + a.z * bb.z + a.w * bb.w;
        }
        df += __shfl_xor(df, 1);
        df += __shfl_xor(df, 2);
        df += __shfl_xor(df, 4);
        sim = df / (norms_x[rnode] * norms_x[cnode]);
    }
    float w = (sim >= THRV) ? sim : 0.0f;
    if (q == 0) {
        ews[e] = w;
        if (w != 0.0f) {
            ATOMIC_ADD_F32(&degL1[gr], w);
            atomicAdd(&cnt[gr], 1);
        }
    }
}

// ========== int8 GEMM (standalone): xq [NN,128] x Wq [128,128] -> int8 hq + hrs ==========

__global__ __launch_bounds__(256) void gemm_nh_k(const int* __restrict__ xqi,
                                                 const float* __restrict__ rs,
                                                 const float* __restrict__ norms_x,
                                                 const int* __restrict__ Wq,
                                                 const float* __restrict__ wcs,
                                                 unsigned int* __restrict__ hq,
                                                 float* __restrict__ hrs, int n) {
    __shared__ int WsQ[32 * 128];     // 16 KB, [k4][col]
    __shared__ int XsQ[32 * 32];      // 4 KB, [row][k4]
    __shared__ float wcss[128];
    int tid = threadIdx.x;
    int row0 = blockIdx.x * 32;
    {
        int4* W4 = reinterpret_cast<int4*>(WsQ);
        const int4* Wg4 = reinterpret_cast<const int4*>(Wq);
        #pragma unroll
        for (int i = 0; i < 4; i++) W4[tid + 256 * i] = Wg4[tid + 256 * i];
        if (tid < 128) wcss[tid] = wcs[tid];
        int r = tid >> 3, p = tid & 7;
        reinterpret_cast<int4*>(XsQ)[tid] =
            reinterpret_cast<const int4*>(xqi + (size_t)(row0 + r) * 32)[p];
    }
    __syncthreads();
    int cg = tid & 31;     // cols 4cg..4cg+3
    int rl = tid >> 5;     // rows rl, rl+8, rl+16, rl+24
    int4 acc[4];
    #pragma unroll
    for (int i = 0; i < 4; i++) acc[i] = make_int4(0, 0, 0, 0);
    for (int k4 = 0; k4 < 32; k4++) {
        int4 wv = reinterpret_cast<const int4*>(WsQ + k4 * 128)[cg];
        #pragma unroll
        for (int r4 = 0; r4 < 4; r4++) {
            int xv = XsQ[(rl + 8 * r4) * 32 + k4];
            acc[r4].x = dot4(xv, wv.x, acc[r4].x);
            acc[r4].y = dot4(xv, wv.y, acc[r4].y);
            acc[r4].z = dot4(xv, wv.z, acc[r4].z);
            acc[r4].w = dot4(xv, wv.w, acc[r4].w);
        }
    }
    float4 wc = reinterpret_cast<const float4*>(wcss)[cg];
    #pragma unroll
    for (int r4 = 0; r4 < 4; r4++) {
        int grow = row0 + rl + 8 * r4;
        float xscale = rs[grow] * norms_x[grow];   // = am_row/127
        float fx = (float)acc[r4].x * xscale * wc.x;
        float fy = (float)acc[r4].y * xscale * wc.y;
        float fz = (float)acc[r4].z * xscale * wc.z;
        float fw = (float)acc[r4].w * xscale * wc.w;
        float am = fmaxf(fmaxf(fabsf(fx), fabsf(fy)), fmaxf(fabsf(fz), fabsf(fw)));
        #pragma unroll
        for (int off = 1; off < 32; off <<= 1) am = fmaxf(am, __shfl_xor(am, off));
        am = fmaxf(am, 1e-20f);
        float qs = 127.0f / am;
        int q0 = __float2int_rn(fx * qs);
        int q1 = __float2int_rn(fy * qs);
        int q2 = __float2int_rn(fz * qs);
        int q3 = __float2int_rn(fw * qs);
        unsigned int u = (q0 & 0xff) | ((q1 & 0xff) << 8) |
                         ((q2 & 0xff) << 16) | ((q3 & 0xff) << 24);
        if (grow < n) {
            hq[(size_t)grow * 32 + cg] = u;
            if (cg == 0) hrs[grow] = am / 127.0f;
        }
    }
}

// ================= scan (cnt -> start exclusive prefix) =================

__global__ __launch_bounds__(512) void scan1_k(const int* __restrict__ in,
                                               int* __restrict__ out,
                                               int* __restrict__ partials, int n) {
    __shared__ int a[1024], b[1024];
    int t = threadIdx.x;
    int base = blockIdx.x * 1024;
    a[t]       = (base + t       < n) ? in[base + t]       : 0;
    a[t + 512] = (base + t + 512 < n) ? in[base + t + 512] : 0;
    __syncthreads();
    int* src = a; int* dst = b;
    for (int off = 1; off < 1024; off <<= 1) {
        #pragma unroll
        for (int q = 0; q < 2; q++) {
            int i = t + q * 512;
            int v = src[i];
            if (i >= off) v += src[i - off];
            dst[i] = v;
        }
        __syncthreads();
        int* tmp = src; src = dst; dst = tmp;
    }
    for (int q = 0; q < 2; q++) {
        int i = t + q * 512;
        if (base + i < n) out[base + i] = i ? src[i - 1] : 0;
    }
    if (t == 0) partials[blockIdx.x] = src[1023];
}

__global__ __launch_bounds__(256) void scan2_k(int* __restrict__ partials, int m) {
    __shared__ int a[256], b[256];
    int t = threadIdx.x;
    a[t] = (t < m) ? partials[t] : 0;
    __syncthreads();
    int* src = a; int* dst = b;
    for (int off = 1; off < 256; off <<= 1) {
        int v = src[t];
        if (t >= off) v += src[t - off];
        dst[t] = v;
        __syncthreads();
        int* tmp = src; src = dst; dst = tmp;
    }
    if (t < m) partials[t] = t ? src[t - 1] : 0;
}

// scan3 + dinvh precompute: dinvh[i] = rsqrt(degL1[i]) * hrs[i % NN]

__global__ void scan3_k(int* __restrict__ start, int* __restrict__ next,
                        const int* __restrict__ partials,
                        const int* __restrict__ cnt,
                        const float* __restrict__ degL1,
                        const float* __restrict__ hrs,
                        float* __restrict__ dinvh, int n) {
    int i = blockIdx.x * 256 + threadIdx.x;
    if (i < n) {
        int v = start[i] + partials[i >> 10];
        start[i] = v;
        next[i] = v;
        if (i == n - 1) start[n] = v + cnt[i];
        int node = (i < NN) ? i : i - NN;
        dinvh[i] = rsqrtf(degL1[i]) * hrs[node];
    }
}

// ===== scatter alive edges: acw = {col, w * dinvh[sb+col]} =====

__global__ void scatter_alive_k(const int* __restrict__ r1, const int* __restrict__ c1,
                                const int* __restrict__ r2, const int* __restrict__ c2,
                                const float* __restrict__ ews,
                                const float* __restrict__ dinvh,
                                int* __restrict__ next, int2* __restrict__ acw) {
    int e = blockIdx.x * 256 + threadIdx.x;
    float w = ews[e];
    if (w == 0.0f) return;
    int gr, c, sb;
    if (e < EE) { gr = r1[e]; c = c1[e]; sb = 0; }
    else        { gr = NN + r2[e - EE]; c = c2[e - EE]; sb = NN; }
    int pos = atomicAdd(&next[gr], 1);
    int2 rec;
    rec.x = c;
    rec.y = __float_as_int(w * dinvh[sb + c]);
    acw[pos] = rec;
}

// ===== CSR aggregate D=128 over int8 h; writes bf16 agg + int8 agg + scales =====

__global__ __launch_bounds__(256) void agg128_fused_k(
        const unsigned short* __restrict__ hq16, const float* __restrict__ hrs,
        const int* __restrict__ start, const int2* __restrict__ acw,
        const float* __restrict__ degL1, const float* __restrict__ bias,
        unsigned int* __restrict__ aggb, unsigned short* __restrict__ xq2,
        float* __restrict__ rs2, float* __restrict__ norms_l2,
        float* __restrict__ degL2) {
    int gr = blockIdx.x * 4 + (threadIdx.x >> 6);
    int lane = threadIdx.x & 63;
    int rnode = (gr < NN) ? gr : gr - NN;
    int j0 = start[gr], j1 = start[gr + 1];
    float2 acc = make_float2(0.f, 0.f);
    for (int j = j0; j < j1; j++) {
        int2 rec = acw[j];
        float wv = __int_as_float(rec.y);        // includes hrs[col]
        unsigned short hv = hq16[(size_t)rec.x * 64 + lane];
        acc.x += (float)(char)(hv & 0xff) * wv;
        acc.y += (float)(char)(hv >> 8) * wv;
    }
    float dr = rsqrtf(degL1[gr]);
    float hr = hrs[rnode];
    unsigned short hs = hq16[(size_t)rnode * 64 + lane];
    float hx = (float)(char)(hs & 0xff) * hr;
    float hy = (float)(char)(hs >> 8) * hr;
    float2 bb = reinterpret_cast<const float2*>(bias)[lane];
    float vx = fmaxf(acc.x * dr + hx * dr * dr + bb.x, 0.0f);
    float vy = fmaxf(acc.y * dr + hy * dr * dr + bb.y, 0.0f);
    aggb[(size_t)gr * 64 + lane] =
        (unsigned int)f2bf(vx) | ((unsigned int)f2bf(vy) << 16);
    float ss = vx * vx + vy * vy;
    float am = fmaxf(vx, vy);                     // non-negative rows
    #pragma unroll
    for (int off = 32; off; off >>= 1) {
        ss += __shfl_xor(ss, off);
        am = fmaxf(am, __shfl_xor(am, off));
    }
    float norm = fmaxf(sqrtf(ss), EPSV);
    am = fmaxf(am, 1e-12f);
    float qs = 127.0f / am;
    int q0 = __float2int_rn(vx * qs);
    int q1 = __float2int_rn(vy * qs);
    xq2[(size_t)gr * 64 + lane] = (unsigned short)((q0 & 0xff) | ((q1 & 0xff) << 8));
    if (lane == 0) {
        rs2[gr] = am / (127.0f * norm);
        norms_l2[gr] = norm;
        degL2[gr] = 1.0f;
    }
}

// ===== FUSED: gemm_nc (blocks 0..GB2) + pass-2 edge sim (rest) =====

__global__ __launch_bounds__(256) void simgemm2_k(
        const unsigned short* __restrict__ xq2, const float* __restrict__ rs2,
        const unsigned int* __restrict__ aggb, const float* __restrict__ norms_l2,
        const int* __restrict__ start, int2* __restrict__ acw,
        float* __restrict__ degL2,
        const int* __restrict__ Wq2, const float* __restrict__ wcs2,
        unsigned short* __restrict__ h2b, int n) {
    __shared__ int XsQ[64 * 33];      // 8.25 KB
    __shared__ int WsQ2[32 * 40];     // 5 KB
    __shared__ float wcss[40];
    __shared__ float rsc[64];
    int tid = threadIdx.x;

    if (blockIdx.x < GB2) {
        // ---------------- gemm_nc path ----------------
        const int* xq2i = (const int*)xq2;
        int row0 = blockIdx.x * 64;
        for (int i = tid; i < 32 * 40; i += 256) WsQ2[i] = Wq2[i];
        if (tid < 40) wcss[tid] = wcs2[tid];
        if (tid < 64) {
            int g = row0 + tid;
            rsc[tid] = rs2[g] * norms_l2[g];    // = am_row/127
        }
        #pragma unroll
        for (int i = 0; i < 2; i++) {
            int idx = tid + 256 * i;            // 0..511 int4s
            int rr = idx >> 3, p = idx & 7;
            int4 v = reinterpret_cast<const int4*>(xq2i + (size_t)(row0 + rr) * 32)[p];
            int* dst = &XsQ[rr * 33 + p * 4];
            dst[0] = v.x; dst[1] = v.y; dst[2] = v.z; dst[3] = v.w;
        }
        __syncthreads();
        int c5 = tid & 7;
        int r  = tid >> 3;
        int acc0[5] = {0, 0, 0, 0, 0}, acc1[5] = {0, 0, 0, 0, 0};
        for (int k4 = 0; k4 < 32; k4++) {
            int xv0 = XsQ[r * 33 + k4];
            int xv1 = XsQ[(r + 32) * 33 + k4];
            #pragma unroll
            for (int c = 0; c < 5; c++) {
                int wv = WsQ2[k4 * 40 + c5 * 5 + c];
                acc0[c] = dot4(xv0, wv, acc0[c]);
                acc1[c] = dot4(xv1, wv, acc1[c]);
            }
        }
        float s0 = rsc[r], s1 = rsc[r + 32];
        int g0 = row0 + r, g1 = row0 + r + 32;
        for (int c = 0; c < 5; c++) {
            float wc = wcss[c5 * 5 + c];
            h2b[(size_t)g0 * 64 + c5 * 5 + c] = f2bf((float)acc0[c] * s0 * wc);
            h2b[(size_t)g1 * 64 + c5 * 5 + c] = f2bf((float)acc1[c] * s1 * wc);
        }
        return;
    }

    // ---------------- sim2 path ----------------
    int gr = (blockIdx.x - GB2) * 4 + (tid >> 6);
    int lane = tid & 63;
    int j0 = start[gr], j1 = start[gr + 1];
    if (j0 == j1) return;
    int set_base = (gr < NN) ? 0 : NN;
    unsigned int au = xq2[(size_t)gr * 64 + lane];
    int a0 = ((int)(au << 24)) >> 24;
    int a1 = ((int)((au << 16) & 0xff000000u)) >> 24;
    float ra = rs2[gr];
    float nr = norms_l2[gr];
    float sum = 0.f;
    for (int j = j0; j < j1; j++) {
        int2 rec = acw[j];
        int cg = set_base + rec.x;
        unsigned int bu = xq2[(size_t)cg * 64 + lane];
        int b0 = ((int)(bu << 24)) >> 24;
        int b1 = ((int)((bu << 16) & 0xff000000u)) >> 24;
        int d = a0 * b0 + a1 * b1;
        #pragma unroll
        for (int off = 32; off; off >>= 1) d += __shfl_xor(d, off);
        float sim = (float)d * ra * rs2[cg];
        if (fabsf(sim - THRV) <= DELTA) {
            unsigned int av = aggb[(size_t)gr * 64 + lane];
            unsigned int bv = aggb[(size_t)cg * 64 + lane];
            float df = bf2f((unsigned short)(av & 0xffff)) *
                       bf2f((unsigned short)(bv & 0xffff)) +
                       bf2f((unsigned short)(av >> 16)) *
                       bf2f((unsigned short)(bv >> 16));
            #pragma unroll
            for (int off = 32; off; off >>= 1) df += __shfl_xor(df, off);
            sim = df / (nr * norms_l2[cg]);
        }
        float w2 = (sim >= THRV) ? sim : 0.0f;
        if (lane == 0) acw[j].y = __float_as_int(w2);
        sum += w2;
    }
    if (lane == 0) degL2[gr] = 1.0f + sum;
}

// ===== CSR aggregate D=40 over bf16 padded h2, fused finish -> f32 aggy =====

__global__ __launch_bounds__(256) void agg40_fused_k(
        const unsigned short* __restrict__ h2b, const int* __restrict__ start,
        const int2* __restrict__ acw, const float* __restrict__ degL2,
        const float* __restrict__ bias, float* __restrict__ aggy) {
    int gr = blockIdx.x * 4 + (threadIdx.x >> 6);
    int lane = threadIdx.x & 63;
    int set_base = (gr < NN) ? 0 : NN;
    int j0 = start[gr], j1 = start[gr + 1];
    bool act = lane < 40;
    float acc = 0.f;
    for (int j = j0; j < j1; j++) {
        int2 rec = acw[j];
        float w2 = __int_as_float(rec.y);
        if (w2 == 0.0f) continue;
        int cg = set_base + rec.x;
        float nv = w2 * rsqrtf(degL2[cg]);
        float hv = act ? bf2f(h2b[(size_t)cg * 64 + lane]) : 0.f;
        acc += hv * nv;
    }
    if (act) {
        float dr = rsqrtf(degL2[gr]);
        float self = bf2f(h2b[(size_t)gr * 64 + lane]);
        aggy[(size_t)gr * 40 + lane] = acc * dr + self * dr * dr + bias[lane];
    }
}

// ================= fusion + log_softmax (thread per node) =================

__global__ __launch_bounds__(256) void fusion_k(const float* __restrict__ y1,
                                                const float* __restrict__ y2,
                                                const float* __restrict__ W1,
                                                const float* __restrict__ b1,
                                                const float* __restrict__ W2,
                                                float* __restrict__ out, int n) {
    __shared__ float W1s[40 * 40];
    __shared__ float b1s[40];
    __shared__ float W2s[40];
    int tid = threadIdx.x;
    for (int i = tid; i < 1600; i += 256) W1s[i] = W1[i];
    if (tid < 40) { b1s[tid] = b1[tid]; W2s[tid] = W2[tid]; }
    __syncthreads();
    int i = blockIdx.x * 256 + tid;
    if (i >= n) return;
    float z1[40], z2[40];
    const float4* y14 = reinterpret_cast<const float4*>(y1 + (size_t)i * 40);
    const float4* y24 = reinterpret_cast<const float4*>(y2 + (size_t)i * 40);
    #pragma unroll
    for (int q = 0; q < 10; q++) {
        float4 a = y14[q], b = y24[q];
        z1[4 * q] = a.x; z1[4 * q + 1] = a.y; z1[4 * q + 2] = a.z; z1[4 * q + 3] = a.w;
        z2[4 * q] = b.x; z2[4 * q + 1] = b.y; z2[4 * q + 2] = b.z; z2[4 * q + 3] = b.w;
    }
    float w1 = 0.f, w2 = 0.f;
    for (int c = 0; c < 40; c++) {
        float s1 = b1s[c], s2 = b1s[c];
        for (int j = 0; j < 40; j++) {
            float ww = W1s[j * 40 + c];
            s1 += z1[j] * ww; s2 += z2[j] * ww;
        }
        float wa = W2s[c];
        w1 += tanhf(s1) * wa; w2 += tanhf(s2) * wa;
    }
    float m = fmaxf(w1, w2);
    float e1 = expf(w1 - m), e2 = expf(w2 - m);
    float inv = 1.0f / (e1 + e2);
    float be1 = e1 * inv, be2 = e2 * inv;
    float fu[40];
    float mx = -1e30f;
    #pragma unroll
    for (int c = 0; c < 40; c++) {
        fu[c] = be1 * z1[c] + be2 * z2[c];
        mx = fmaxf(mx, fu[c]);
    }
    float se = 0.f;
    #pragma unroll
    for (int c = 0; c < 40; c++) se += expf(fu[c] - mx);
    float ls = logf(se);
    float4* o4 = reinterpret_cast<float4*>(out + (size_t)i * 40);
    #pragma unroll
    for (int q = 0; q < 10; q++) {
        float4 v;
        v.x = fu[4 * q] - mx - ls; v.y = fu[4 * q + 1] - mx - ls;
        v.z = fu[4 * q + 2] - mx - ls; v.w = fu[4 * q + 3] - mx - ls;
        o4[q] = v;
    }
}

// ================= host =================

extern "C" void kernel_launch(void* const* d_in, const int* in_sizes, int n_in,
                              void* d_out, int out_size, void* d_ws, size_t ws_size,
                              hipStream_t stream) {
    (void)in_sizes; (void)n_in; (void)out_size; (void)ws_size;
    const float* x   = (const float*)d_in[0];
    const float* Wg1 = (const float*)d_in[1];
    const float* bg1 = (const float*)d_in[2];
    const float* Wg2 = (const float*)d_in[3];
    const float* bg2 = (const float*)d_in[4];
    const float* Wa1 = (const float*)d_in[5];
    const float* ba1 = (const float*)d_in[6];
    const float* Wa2 = (const float*)d_in[7];
    const int* ei1 = (const int*)d_in[8];
    const int* ei2 = (const int*)d_in[9];
    const int *r1 = ei1, *c1 = ei1 + EE;
    const int *r2 = ei2, *c2 = ei2 + EE;
    float* out = (float*)d_out;

    // ---- workspace carve (f32 words); ~155 MB ----
    float* wp = (float*)d_ws;
    float* norms_x  = wp;  wp += NN;
    float* norms_l2 = wp;  wp += 2 * NN;
    float* rs       = wp;  wp += NN;
    float* degL1    = wp;  wp += 2 * NN;
    float* degL2    = wp;  wp += 2 * NN;
    float* hrs      = wp;  wp += NN;
    float* dinvh    = wp;  wp += 2 * NN;
    int*   cnt      = (int*)wp;  wp += 2 * NN;
    int*   start    = (int*)wp;  wp += 2 * NN + 8;
    int*   next     = (int*)wp;  wp += 2 * NN;
    int*   partials = (int*)wp;  wp += 512;
    int*   Wq       = (int*)wp;  wp += 32 * 128;                 // packed int8 W_gc1
    float* wcs      = wp;  wp += 128;
    int*   Wq2      = (int*)wp;  wp += 32 * 40;                  // packed int8 W_gc2
    float* wcs2     = wp;  wp += 40;
    float* ews      = wp;  wp += 2 * EE;                         // rs2 overlays after scatter
    int2*  acw      = (int2*)wp; wp += (size_t)2 * 2 * EE;       // worst-case all alive
    unsigned int* hq = (unsigned int*)wp; wp += (size_t)NN * 32;    // NN x 128 int8
    unsigned short* h2b = (unsigned short*)wp; wp += (size_t)2 * NN * 32;  // 2N x 64 bf16
    unsigned int*   aggb = (unsigned int*)wp;  wp += (size_t)2 * NN * 64;  // 2N x 128 bf16
    unsigned short* xq2 = (unsigned short*)wp; wp += (size_t)2 * NN * 32;  // 2N x 128 int8
    unsigned short* xq = (unsigned short*)aggb;  // pass-1 int8 x rows (dead before aggb)
    float* rs2 = ews;                            // ews dead after scatter_alive
    float* aggy = (float*)aggb;                  // aggb dead after simgemm2

    const int twoN = 2 * NN;
    const int twoE = 2 * EE;
    const int scan_blocks = (twoN + 1023) / 1024;    // 196

    // ---- pass 1: quant weights + norms + edge sims; int8 gemm for h ----
    quantW12_k<<<168, 64, 0, stream>>>(Wg1, Wq, wcs, Wg2, Wq2, wcs2);
    normalize_k<<<NN / 4, 256, 0, stream>>>(x, xq, rs, norms_x, degL1, cnt);
    edge_sim1_k<<<twoE / 32, 256, 0, stream>>>(xq, rs, x, norms_x,
                                               r1, c1, r2, c2, ews, degL1, cnt);
    gemm_nh_k<<<(NN + 31) / 32, 256, 0, stream>>>((const int*)xq, rs, norms_x,
                                                  Wq, wcs, hq, hrs, NN);

    // ---- CSR over alive edges (+ dinvh precompute) ----
    scan1_k<<<scan_blocks, 512, 0, stream>>>(cnt, start, partials, twoN);
    scan2_k<<<1, 256, 0, stream>>>(partials, scan_blocks);
    scan3_k<<<(twoN + 255) / 256, 256, 0, stream>>>(start, next, partials, cnt,
                                                    degL1, hrs, dinvh, twoN);
    scatter_alive_k<<<twoE / 256, 256, 0, stream>>>(r1, c1, r2, c2, ews, dinvh,
                                                    next, acw);

    // ---- layer 1 aggregate ----
    agg128_fused_k<<<twoN / 4, 256, 0, stream>>>((const unsigned short*)hq, hrs,
                                                 start, acw, degL1, bg1,
                                                 aggb, xq2, rs2, norms_l2, degL2);

    // ---- layer 2: fused (gemm_nc || edge_sim2) ----
    simgemm2_k<<<GB2 + twoN / 4, 256, 0, stream>>>(xq2, rs2, aggb, norms_l2,
                                                   start, acw, degL2,
                                                   Wq2, wcs2, h2b, twoN);
    agg40_fused_k<<<twoN / 4, 256, 0, stream>>>(h2b, start, acw, degL2, bg2, aggy);
    fusion_k<<<(NN + 255) / 256, 256, 0, stream>>>(aggy, aggy + (size_t)NN * 40,
                                                   Wa1, ba1, Wa2, out, NN);
}